// Round 7
// baseline (343.874 us; speedup 1.0000x reference)
//
#include <hip/hip_runtime.h>
#include <math.h>

#define N_NODES 50000
#define N_EDGES 1600000
#define C 64
#define OUTC 7

#define NB 196         // coarse buckets: dst >> 8  (49999>>8 = 195)
#define BCAP 10240     // bucket capacity (mean 8192, sigma ~90)
#define CHUNK 4096     // edges per phase-1 workgroup

// ---------------- CSR build, phase 1: coarse binning ----------------
// Pack edge as (dst<<16)|src (both < 65536). bucket = v >> 24 (= dst>>8).
__global__ __launch_bounds__(256) void bin_kernel(const int* __restrict__ src,
                                                  const int* __restrict__ dst,
                                                  unsigned int* __restrict__ buckets,
                                                  int* __restrict__ gcursor) {
    __shared__ unsigned int staged[CHUNK];          // 16 KB
    __shared__ int hist[NB], scanb[NB], cur[NB], baseb[NB];
    const int tid = threadIdx.x;
    const int base = blockIdx.x * CHUNK;
    int n = N_EDGES - base; if (n > CHUNK) n = CHUNK;  // multiple of 4

    for (int b = tid; b < NB; b += 256) { hist[b] = 0; cur[b] = 0; }
    __syncthreads();

    const int4* src4 = (const int4*)(src + base);
    const int4* dst4 = (const int4*)(dst + base);
    unsigned int v[16];
    int nv = n >> 2;
#pragma unroll
    for (int k = 0; k < 4; ++k) {
        int i4 = k * 256 + tid;
        if (i4 < nv) {
            int4 s4 = src4[i4];
            int4 d4 = dst4[i4];
            unsigned int d0 = (unsigned int)d4.x, d1 = (unsigned int)d4.y;
            unsigned int d2 = (unsigned int)d4.z, d3 = (unsigned int)d4.w;
            v[k * 4 + 0] = (d0 << 16) | (unsigned int)s4.x;
            v[k * 4 + 1] = (d1 << 16) | (unsigned int)s4.y;
            v[k * 4 + 2] = (d2 << 16) | (unsigned int)s4.z;
            v[k * 4 + 3] = (d3 << 16) | (unsigned int)s4.w;
            atomicAdd(&hist[d0 >> 8], 1);
            atomicAdd(&hist[d1 >> 8], 1);
            atomicAdd(&hist[d2 >> 8], 1);
            atomicAdd(&hist[d3 >> 8], 1);
        }
    }
    __syncthreads();
    if (tid == 0) {
        int run = 0;
        for (int b = 0; b < NB; ++b) { scanb[b] = run; run += hist[b]; }
    }
    __syncthreads();
#pragma unroll
    for (int k = 0; k < 4; ++k) {
        int i4 = k * 256 + tid;
        if (i4 < nv) {
#pragma unroll
            for (int q = 0; q < 4; ++q) {
                unsigned int w = v[k * 4 + q];
                int b = w >> 24;
                int p = scanb[b] + atomicAdd(&cur[b], 1);
                staged[p] = w;
            }
        }
    }
    __syncthreads();
    if (tid < NB) baseb[tid] = atomicAdd(&gcursor[tid], hist[tid]);
    __syncthreads();
    for (int i = tid; i < n; i += 256) {
        unsigned int w = staged[i];
        int b = w >> 24;
        buckets[(size_t)b * BCAP + baseb[b] + (i - scanb[b])] = w;
    }
}

// ---------------- CSR build, phase 2: per-bucket local CSR ----------------
__global__ __launch_bounds__(256) void build_csr(const unsigned int* __restrict__ buckets,
                                                 const int* __restrict__ gcursor,
                                                 unsigned int* __restrict__ csr,
                                                 int* __restrict__ off) {
    __shared__ int hist[256], part[256], offx[256], cur[256];
    __shared__ int gl[NB];
    __shared__ int s_cnt, s_base;
    const int tid = threadIdx.x;
    const int b = blockIdx.x;

    hist[tid] = 0;
    cur[tid] = 0;
    if (tid < NB) gl[tid] = gcursor[tid];
    __syncthreads();
    if (tid == 0) {
        int bs = 0;
        for (int i = 0; i < b; ++i) bs += gl[i];
        s_base = bs;
        s_cnt = gl[b];
    }
    __syncthreads();
    const int cnt = s_cnt;
    const int gbase = s_base;
    const unsigned int* bk = buckets + (size_t)b * BCAP;

    for (int i = tid; i < cnt; i += 256) {
        atomicAdd(&hist[(bk[i] >> 16) & 255], 1);
    }
    __syncthreads();
    part[tid] = hist[tid];
    __syncthreads();
    for (int d = 1; d < 256; d <<= 1) {
        int t = (tid >= d) ? part[tid - d] : 0;
        __syncthreads();
        part[tid] += t;
        __syncthreads();
    }
    offx[tid] = (tid == 0) ? 0 : part[tid - 1];
    __syncthreads();
    int node = b * 256 + tid;
    if (node < N_NODES) off[node] = gbase + offx[tid];
    if (b == NB - 1 && tid == 0) off[N_NODES] = gbase + cnt;
    for (int i = tid; i < cnt; i += 256) {
        unsigned int w = bk[i];
        int dl = (w >> 16) & 255;
        int p = offx[dl] + atomicAdd(&cur[dl], 1);
        csr[gbase + p] = w & 0xFFFFu;
    }
}

// ---------------- dense linears ----------------

// 4 waves/block; wave owns channels [wave*16, wave*16+16), lane = row.
// W base is wave-uniform -> scalar (s_load/K$) path; 782 blocks = 3128 waves
// (~12/CU) hide the scalar-load latency that capped the thread-per-row
// version at 7% occupancy / 60 us.
__global__ __launch_bounds__(256) void linear64_split(const float* __restrict__ x,
                                                      const float* __restrict__ W,
                                                      float* __restrict__ out) {
    const int wave = threadIdx.x >> 6;
    const int lane = threadIdx.x & 63;
    const int r = blockIdx.x * 64 + lane;
    if (r >= N_NODES) return;
    float4 xr[16];
    const float4* xp = (const float4*)(x + (size_t)r * 64);
#pragma unroll
    for (int j = 0; j < 16; ++j) xr[j] = xp[j];
    const float* xf = (const float*)xr;

    const float* Wp = W + wave * 16 * 64;   // wave-uniform
    float4* op = (float4*)(out + (size_t)r * 64 + wave * 16);
    for (int c0 = 0; c0 < 16; c0 += 8) {
        float acc[8] = {0.f, 0.f, 0.f, 0.f, 0.f, 0.f, 0.f, 0.f};
#pragma unroll
        for (int k = 0; k < 64; ++k) {
            float xv = xf[k];
#pragma unroll
            for (int j = 0; j < 8; ++j)
                acc[j] += xv * Wp[(c0 + j) * 64 + k];  // uniform address
        }
        op[c0 >> 2]       = make_float4(acc[0], acc[1], acc[2], acc[3]);
        op[(c0 >> 2) + 1] = make_float4(acc[4], acc[5], acc[6], acc[7]);
    }
}

// k-split across lane pairs: even lane k in [0,32), odd k in [32,64);
// 7 shfl_xor combine; even lane writes the stride-8 padded row.
__global__ __launch_bounds__(256) void linear7_rows(const float* __restrict__ x,
                                                    const float* __restrict__ W,
                                                    float* __restrict__ out) {
    int gid = blockIdx.x * 256 + threadIdx.x;
    int r = gid >> 1;
    int half = gid & 1;
    if (r >= N_NODES) return;
    float4 xr[8];
    const float4* xp = (const float4*)(x + (size_t)r * 64 + half * 32);
#pragma unroll
    for (int j = 0; j < 8; ++j) xr[j] = xp[j];
    const float* xf = (const float*)xr;

    float acc[7] = {0.f, 0.f, 0.f, 0.f, 0.f, 0.f, 0.f};
#pragma unroll
    for (int k = 0; k < 32; ++k) {
        float xv = xf[k];
#pragma unroll
        for (int j = 0; j < 7; ++j)
            acc[j] += xv * W[j * 64 + half * 32 + k];  // 2 addrs/wave, L1-hit
    }
#pragma unroll
    for (int j = 0; j < 7; ++j) acc[j] += __shfl_xor(acc[j], 1, 64);
    if (half == 0) {
        float4* op = (float4*)(out + (size_t)r * 8);
        op[0] = make_float4(acc[0], acc[1], acc[2], acc[3]);
        op[1] = make_float4(acc[4], acc[5], acc[6], 0.f);
    }
}

// ---------------- gather aggregation (float4-vectorized) ----------------

// Lane map: slot = lane>>4 (4 edge slots), ch4 = lane&15 (4 channels each).
__global__ __launch_bounds__(256) void gather64(const int* __restrict__ off,
                                                const unsigned int* __restrict__ csr_src,
                                                const float* __restrict__ t,
                                                const float* __restrict__ b,
                                                float* __restrict__ out,
                                                int do_relu) {
    int node = blockIdx.x * 4 + (threadIdx.x >> 6);
    if (node >= N_NODES) return;
    const int lane = threadIdx.x & 63;
    const int slot = lane >> 4;
    const int ch4  = lane & 15;
    int e0 = off[node], e1 = off[node + 1];
    const float4* t4 = (const float4*)t;
    float sx = 0.f, sy = 0.f, sz = 0.f, sw = 0.f;
    for (int e = e0; e < e1; e += 8) {
        int i0 = e + slot;
        int i1 = e + 4 + slot;
        bool p0 = i0 < e1, p1 = i1 < e1;
        unsigned int a0 = csr_src[p0 ? i0 : e];
        unsigned int a1 = csr_src[p1 ? i1 : e];
        float4 v0 = t4[(size_t)a0 * 16 + ch4];
        float4 v1 = t4[(size_t)a1 * 16 + ch4];
        if (p0) { sx += v0.x; sy += v0.y; sz += v0.z; sw += v0.w; }
        if (p1) { sx += v1.x; sy += v1.y; sz += v1.z; sw += v1.w; }
    }
    sx += __shfl_xor(sx, 16, 64); sy += __shfl_xor(sy, 16, 64);
    sz += __shfl_xor(sz, 16, 64); sw += __shfl_xor(sw, 16, 64);
    sx += __shfl_xor(sx, 32, 64); sy += __shfl_xor(sy, 32, 64);
    sz += __shfl_xor(sz, 32, 64); sw += __shfl_xor(sw, 32, 64);
    if (lane < 16) {
        const float4 bb = ((const float4*)b)[ch4];
        float4 r;
        r.x = sx + bb.x; r.y = sy + bb.y; r.z = sz + bb.z; r.w = sw + bb.w;
        if (do_relu) {
            r.x = fmaxf(r.x, 0.f); r.y = fmaxf(r.y, 0.f);
            r.z = fmaxf(r.z, 0.f); r.w = fmaxf(r.w, 0.f);
        }
        ((float4*)(out + (size_t)node * 64))[ch4] = r;
    }
}

// 7-ch gather + bias + log_softmax. slot = lane>>1 (32 edge slots), h = lane&1.
__global__ __launch_bounds__(256) void gather7_lsm(const int* __restrict__ off,
                                                   const unsigned int* __restrict__ csr_src,
                                                   const float* __restrict__ t3,
                                                   const float* __restrict__ b,
                                                   float* __restrict__ out) {
    int node = blockIdx.x * 4 + (threadIdx.x >> 6);
    if (node >= N_NODES) return;
    const int lane = threadIdx.x & 63;
    const int slot = lane >> 1;
    const int h    = lane & 1;
    int e0 = off[node], e1 = off[node + 1];
    const float4* t4 = (const float4*)t3;
    float sx = 0.f, sy = 0.f, sz = 0.f, sw = 0.f;
    for (int e = e0 + slot; e < e1; e += 32) {
        unsigned int s = csr_src[e];
        float4 v = t4[(size_t)s * 2 + h];
        sx += v.x; sy += v.y; sz += v.z; sw += v.w;
    }
#pragma unroll
    for (int d = 2; d <= 32; d <<= 1) {
        sx += __shfl_xor(sx, d, 64); sy += __shfl_xor(sy, d, 64);
        sz += __shfl_xor(sz, d, 64); sw += __shfl_xor(sw, d, 64);
    }
    float z0 = sx + b[h * 4 + 0];
    float z1 = sy + b[h * 4 + 1];
    float z2 = sz + b[h * 4 + 2];
    float z3 = (h == 0) ? (sw + b[3]) : -1e30f;
    float m = fmaxf(fmaxf(z0, z1), fmaxf(z2, z3));
    m = fmaxf(m, __shfl_xor(m, 1, 64));
    float ex = __expf(z0 - m) + __expf(z1 - m) + __expf(z2 - m) + __expf(z3 - m);
    ex += __shfl_xor(ex, 1, 64);
    float l = m + __logf(ex);
    if (lane < 2) {
        float* o = out + (size_t)node * 7 + h * 4;
        o[0] = z0 - l; o[1] = z1 - l; o[2] = z2 - l;
        if (h == 0) o[3] = z3 - l;
    }
}

extern "C" void kernel_launch(void* const* d_in, const int* in_sizes, int n_in,
                              void* d_out, int out_size, void* d_ws, size_t ws_size,
                              hipStream_t stream) {
    const float* x  = (const float*)d_in[0];
    const int*   ei = (const int*)d_in[1];
    const float* W1 = (const float*)d_in[2];
    const float* b1 = (const float*)d_in[3];
    const float* W2 = (const float*)d_in[4];
    const float* b2 = (const float*)d_in[5];
    const float* W3 = (const float*)d_in[6];
    const float* b3 = (const float*)d_in[7];
    float* out = (float*)d_out;

    const int* src = ei;
    const int* dst = ei + N_EDGES;

    float* A = (float*)d_ws;                       // 12.8 MB
    float* B = A + (size_t)N_NODES * C;            // 12.8 MB
    unsigned int* csr = (unsigned int*)(B + (size_t)N_NODES * C);
    int* off     = (int*)(csr + N_EDGES);          // 50001
    int* gcursor = off + N_NODES + 8;              // 196
    unsigned int* buckets = (unsigned int*)A;      // aliases A (8.03 MB)

    const int l64grid = (N_NODES + 63) / 64;       // 782 blocks x 4 waves
    const int l7grid  = (2 * N_NODES + 255) / 256; // 391
    const int ngrid   = (N_NODES + 3) / 4;

    // ---- CSR build
    hipMemsetAsync(gcursor, 0, NB * sizeof(int), stream);
    bin_kernel<<<(N_EDGES + CHUNK - 1) / CHUNK, 256, 0, stream>>>(src, dst, buckets, gcursor);
    build_csr<<<NB, 256, 0, stream>>>(buckets, gcursor, csr, off);

    // ---- layer 1 (A free after build_csr)
    linear64_split<<<l64grid, 256, 0, stream>>>(x, W1, A);
    gather64<<<ngrid, 256, 0, stream>>>(off, csr, A, b1, B, 1);

    // ---- layer 2
    linear64_split<<<l64grid, 256, 0, stream>>>(B, W2, A);
    gather64<<<ngrid, 256, 0, stream>>>(off, csr, A, b2, B, 1);

    // ---- layer 3
    linear7_rows<<<l7grid, 256, 0, stream>>>(B, W3, A);
    gather7_lsm<<<ngrid, 256, 0, stream>>>(off, csr, A, b3, out);
}